// Round 1
// baseline (21.088 us; speedup 1.0000x reference)
//
#include <hip/hip_runtime.h>

// IntensityTransform: out[b,h,w,c] = it[b, clip(rint(255*im[b,h,w,c]),0,255), c]
// im: [16,512,512,3] f32, it: [16,256,3] f32, out: [16,512,512,3] f32.
// Memory-bound: ~100 MB total traffic -> ~16 us floor at 6.3 TB/s.

#define NB 16
#define HW (512 * 512)
#define NC 3
#define NI 256
#define ELEMS_PER_BATCH (HW * NC)          // 786432
#define VEC4_PER_BATCH (ELEMS_PER_BATCH/4) // 196608
#define BLOCKS_PER_BATCH 64
#define THREADS 256

__global__ __launch_bounds__(THREADS) void intensity_lut_kernel(
    const float* __restrict__ im,
    const float* __restrict__ it,
    float* __restrict__ out)
{
    __shared__ float lut[NI * NC];  // 3 KB per block

    const int b = blockIdx.y;

    // Stage this batch's LUT into LDS (768 floats, 3 iterations of 256 threads).
    const float* itb = it + (size_t)b * (NI * NC);
    for (int i = threadIdx.x; i < NI * NC; i += THREADS) lut[i] = itb[i];
    __syncthreads();

    const float4* __restrict__ im4  = (const float4*)(im  + (size_t)b * ELEMS_PER_BATCH);
    float4* __restrict__       out4 = (float4*)      (out + (size_t)b * ELEMS_PER_BATCH);

    const int stride = BLOCKS_PER_BATCH * THREADS;
    for (int v = blockIdx.x * THREADS + threadIdx.x; v < VEC4_PER_BATCH; v += stride) {
        float4 x = im4[v];

        // flat element index base = 4*v; channel = (4*v + j) % 3; 4 % 3 == 1 -> c0 = v % 3
        int c0 = v % 3;
        int c1 = c0 + 1; if (c1 == 3) c1 = 0;
        int c2 = c1 + 1; if (c2 == 3) c2 = 0;
        // 4th element channel == c0 again (c0+3 mod 3)

        // rintf = round-half-to-even under default RNE mode, matching np.round/jnp.round.
        int i0 = (int)rintf(255.0f * x.x);
        int i1 = (int)rintf(255.0f * x.y);
        int i2 = (int)rintf(255.0f * x.z);
        int i3 = (int)rintf(255.0f * x.w);
        i0 = min(max(i0, 0), 255);
        i1 = min(max(i1, 0), 255);
        i2 = min(max(i2, 0), 255);
        i3 = min(max(i3, 0), 255);

        float4 y;
        y.x = lut[i0 * NC + c0];
        y.y = lut[i1 * NC + c1];
        y.z = lut[i2 * NC + c2];
        y.w = lut[i3 * NC + c0];

        out4[v] = y;
    }
}

extern "C" void kernel_launch(void* const* d_in, const int* in_sizes, int n_in,
                              void* d_out, int out_size, void* d_ws, size_t ws_size,
                              hipStream_t stream) {
    const float* im = (const float*)d_in[0];
    const float* it = (const float*)d_in[1];
    float* out = (float*)d_out;

    dim3 grid(BLOCKS_PER_BATCH, NB);
    intensity_lut_kernel<<<grid, THREADS, 0, stream>>>(im, it, out);
}

// Round 3
// 20.987 us; speedup vs baseline: 1.0048x; 1.0048x over previous
//
#include <hip/hip_runtime.h>

// IntensityTransform: out[b,h,w,c] = it[b, clip(rint(255*im[b,h,w,c]),0,255), c]
// im: [16,512,512,3] f32, it: [16,256,3] f32, out: [16,512,512,3] f32.
// Memory-bound: ~100 MB total traffic -> ~16 us floor at ~6.3 TB/s achievable.
//
// Round 3: same as round 2 but with native ext_vector float4 so
// __builtin_nontemporal_store compiles (HIP_vector_type is a class -> rejected).

#define NB 16
#define HW (512 * 512)
#define NC 3
#define NI 256
#define ELEMS_PER_BATCH (HW * NC)            // 786432
#define VEC4_PER_BATCH (ELEMS_PER_BATCH / 4) // 196608
#define BLOCKS_PER_BATCH 128
#define THREADS 256
#define VPT 6  // float4s per thread: 196608 / (128*256) = 6 exactly
#define VSTRIDE (BLOCKS_PER_BATCH * THREADS) // 32768

typedef float f32x4 __attribute__((ext_vector_type(4)));

__global__ __launch_bounds__(THREADS) void intensity_lut_kernel(
    const float* __restrict__ im,
    const float* __restrict__ it,
    float* __restrict__ out)
{
    __shared__ float lut[NI * NC];  // 3 KB per block

    const int b = blockIdx.y;

    // Stage this batch's LUT into LDS (768 floats).
    const float* itb = it + (size_t)b * (NI * NC);
    for (int i = threadIdx.x; i < NI * NC; i += THREADS) lut[i] = itb[i];
    __syncthreads();

    const f32x4* __restrict__ im4  = (const f32x4*)(im  + (size_t)b * ELEMS_PER_BATCH);
    f32x4* __restrict__       out4 = (f32x4*)      (out + (size_t)b * ELEMS_PER_BATCH);

    const int v0 = blockIdx.x * THREADS + threadIdx.x;

    // Issue all 6 global loads first (compile-time indices -> registers, 6 in flight).
    f32x4 x[VPT];
#pragma unroll
    for (int k = 0; k < VPT; ++k) x[k] = im4[v0 + k * VSTRIDE];

#pragma unroll
    for (int k = 0; k < VPT; ++k) {
        const int v = v0 + k * VSTRIDE;

        // channel of element 4*v: 4%3==1 -> c0 = v % 3
        int c0 = v % 3;
        int c1 = c0 + 1; if (c1 == 3) c1 = 0;
        int c2 = c1 + 1; if (c2 == 3) c2 = 0;

        // rintf = round-half-to-even (RNE), matching np.round/jnp.round.
        int i0 = (int)rintf(255.0f * x[k].x);
        int i1 = (int)rintf(255.0f * x[k].y);
        int i2 = (int)rintf(255.0f * x[k].z);
        int i3 = (int)rintf(255.0f * x[k].w);
        i0 = min(max(i0, 0), 255);
        i1 = min(max(i1, 0), 255);
        i2 = min(max(i2, 0), 255);
        i3 = min(max(i3, 0), 255);

        f32x4 y;
        y.x = lut[i0 * NC + c0];
        y.y = lut[i1 * NC + c1];
        y.z = lut[i2 * NC + c2];
        y.w = lut[i3 * NC + c0];

        __builtin_nontemporal_store(y, &out4[v]);
    }
}

extern "C" void kernel_launch(void* const* d_in, const int* in_sizes, int n_in,
                              void* d_out, int out_size, void* d_ws, size_t ws_size,
                              hipStream_t stream) {
    const float* im = (const float*)d_in[0];
    const float* it = (const float*)d_in[1];
    float* out = (float*)d_out;

    dim3 grid(BLOCKS_PER_BATCH, NB);
    intensity_lut_kernel<<<grid, THREADS, 0, stream>>>(im, it, out);
}